// Round 7
// baseline (414.557 us; speedup 1.0000x reference)
//
#include <hip/hip_runtime.h>

#define H    64
#define F    256
#define NSEG 256
#define SCB  2048   // scan elements per block
#define MB   64     // qkv node rows per block
#define KC   32     // qkv K chunk

typedef float  f32x4v __attribute__((ext_vector_type(4)));
typedef short  bf16x8 __attribute__((ext_vector_type(8)));

// ---------------------------------------------------------------------------
// Kernel 0: transpose+split W (3 x [256,64] fp32) into Wt[mat][j][k] bf16
// hi/lo (truncation split: w = hi + lo + O(2^-17)).  192 blocks = (mat,j);
// thread t = k.  Tiny (~196KB out).
// ---------------------------------------------------------------------------
__global__ __launch_bounds__(256) void w_convert(
    const float* __restrict__ Wq, const float* __restrict__ Wk,
    const float* __restrict__ Wv,
    unsigned short* __restrict__ wt_hi, unsigned short* __restrict__ wt_lo)
{
    const int b   = blockIdx.x;        // mat*64 + j
    const int mat = b >> 6;
    const int j   = b & 63;
    const int t   = threadIdx.x;       // k
    const float* W = (mat == 0) ? Wq : (mat == 1) ? Wk : Wv;
    float f = W[t * H + j];
    unsigned u = __float_as_uint(f);
    unsigned short hi = (unsigned short)(u >> 16);
    float rf = f - __uint_as_float(u & 0xFFFF0000u);
    unsigned short lo = (unsigned short)(__float_as_uint(rf) >> 16);
    const size_t o = (size_t)b * F + t;
    wt_hi[o] = hi;
    wt_lo[o] = lo;
}

// ---------------------------------------------------------------------------
// Kernel 1: QKV projection via split-bf16 MFMA + fused in-degree histogram.
// Block = 256 thr (4 waves), 64 node rows.  Wave w owns m-tile w (16 rows),
// computes all 3 matrices x 4 n-tiles with mfma_f32_16x16x32_bf16:
//   acc += xh*wh + xh*wl + xl*wh   (xl*wl ~ 2^-17, dropped)
// x chunk (64 x 32 k) split to bf16 hi/lo in LDS (80B row stride: 16B-aligned
// b128 reads, 2-way banks = free).  B frags are 16B global loads from the
// pre-transposed Wt (L1/L2-resident).  FLOP floor ~7us vs 31us fp32-VALU.
// ---------------------------------------------------------------------------
__global__ __launch_bounds__(256) void qkv_mfma_hist(
    const float* __restrict__ x,
    const unsigned short* __restrict__ wt_hi,
    const unsigned short* __restrict__ wt_lo,
    const float* __restrict__ bq, const float* __restrict__ bk,
    const float* __restrict__ bv,
    float* __restrict__ q, float* __restrict__ k, float* __restrict__ v,
    const int* __restrict__ ei, int* __restrict__ counts,
    int N, int E)
{
    __shared__ unsigned short xs_hi[MB * 40];   // 40-short (80B) row stride
    __shared__ unsigned short xs_lo[MB * 40];

    const int t = threadIdx.x;

    // --- fused histogram (independent fire-and-forget atomics) ---
    {
        int e = blockIdx.x * 1024 + t;
        #pragma unroll
        for (int u = 0; u < 4; ++u) {
            if (e < E) {
                int dst = ei[E + e];
                dst = min(max(dst, 0), N - 1);
                atomicAdd(&counts[dst], 1);
            }
            e += 256;
        }
    }

    const int block0 = blockIdx.x * MB;
    const int rows = min(MB, N - block0);

    const int lane = t & 63;
    const int w    = t >> 6;       // wave id = m-tile
    const int l15  = lane & 15;
    const int quad = lane >> 4;

    f32x4v acc[12];                // [mat*4 + ntile]
    #pragma unroll
    for (int i = 0; i < 12; ++i) acc[i] = (f32x4v)0.f;

    const char* ahp = (const char*)xs_hi + ((w * 16 + l15) * 80 + quad * 16);
    const char* alp = (const char*)xs_lo + ((w * 16 + l15) * 80 + quad * 16);

    for (int kb = 0; kb < F; kb += KC) {
        // stage x[block0..+64][kb..+32] as bf16 hi/lo
        __syncthreads();
        #pragma unroll
        for (int it = 0; it < 2; ++it) {
            int idx = t + it * 256;
            int r  = idx >> 3;
            int fc = idx & 7;
            float4 val = (r < rows)
                ? *(const float4*)(x + (size_t)(block0 + r) * F + kb + fc * 4)
                : make_float4(0.f, 0.f, 0.f, 0.f);
            unsigned short h[4], l[4];
            const float ff[4] = {val.x, val.y, val.z, val.w};
            #pragma unroll
            for (int u = 0; u < 4; ++u) {
                unsigned ub = __float_as_uint(ff[u]);
                h[u] = (unsigned short)(ub >> 16);
                float rf = ff[u] - __uint_as_float(ub & 0xFFFF0000u);
                l[u] = (unsigned short)(__float_as_uint(rf) >> 16);
            }
            unsigned short* dh = &xs_hi[r * 40 + fc * 4];
            unsigned short* dl = &xs_lo[r * 40 + fc * 4];
            #pragma unroll
            for (int u = 0; u < 4; ++u) { dh[u] = h[u]; dl[u] = l[u]; }
        }
        __syncthreads();

        const bf16x8 ah = *(const bf16x8*)ahp;
        const bf16x8 al = *(const bf16x8*)alp;

        #pragma unroll
        for (int mat = 0; mat < 3; ++mat) {
            #pragma unroll
            for (int nt = 0; nt < 4; ++nt) {
                const size_t wo = ((size_t)(mat * 64 + nt * 16 + l15)) * F
                                  + kb + quad * 8;
                const bf16x8 bh = *(const bf16x8*)(wt_hi + wo);
                const bf16x8 bl = *(const bf16x8*)(wt_lo + wo);
                f32x4v a = acc[mat * 4 + nt];
                a = __builtin_amdgcn_mfma_f32_16x16x32_bf16(ah, bh, a, 0, 0, 0);
                a = __builtin_amdgcn_mfma_f32_16x16x32_bf16(ah, bl, a, 0, 0, 0);
                a = __builtin_amdgcn_mfma_f32_16x16x32_bf16(al, bh, a, 0, 0, 0);
                acc[mat * 4 + nt] = a;
            }
        }
    }

    // epilogue: C layout col = lane&15, row = quad*4 + reg  (m89-verified)
    float* outs[3] = {q, k, v};
    const float* biases[3] = {bq, bk, bv};
    #pragma unroll
    for (int mat = 0; mat < 3; ++mat) {
        float* dst = outs[mat];
        #pragma unroll
        for (int nt = 0; nt < 4; ++nt) {
            const int col = nt * 16 + l15;
            const float bb = biases[mat][col];
            #pragma unroll
            for (int r = 0; r < 4; ++r) {
                const int node = block0 + w * 16 + quad * 4 + r;
                if (node < N)
                    dst[(size_t)node * H + col] = acc[mat * 4 + nt][r] + bb;
            }
        }
    }
}

// ---------------------------------------------------------------------------
// Scan phase A/B/C: exclusive scan of padded (x4) per-node counts.
// ---------------------------------------------------------------------------
__global__ __launch_bounds__(256) void scanA(
    const int* __restrict__ counts, int* __restrict__ offsets,
    int* __restrict__ bsum, int n)
{
    __shared__ int ps[256];
    const int t = threadIdx.x;
    const int i0 = blockIdx.x * SCB + t * 8;
    int loc[8];
    int s = 0;
    #pragma unroll
    for (int u = 0; u < 8; ++u) {
        int i = i0 + u;
        int c = (i < n) ? ((counts[i] + 3) & ~3) : 0;
        loc[u] = s; s += c;
    }
    ps[t] = s;
    __syncthreads();
    for (int off = 1; off < 256; off <<= 1) {
        int a = (t >= off) ? ps[t - off] : 0;
        __syncthreads();
        ps[t] += a;
        __syncthreads();
    }
    const int base = ps[t] - s;
    #pragma unroll
    for (int u = 0; u < 8; ++u) {
        int i = i0 + u;
        if (i < n) offsets[i] = base + loc[u];
    }
    if (t == 255) bsum[blockIdx.x] = ps[255];
}

__global__ void scanB(int* __restrict__ bsum, int nb)
{
    if (threadIdx.x == 0 && blockIdx.x == 0) {
        int run = 0;
        for (int i = 0; i < nb; ++i) { int v = bsum[i]; bsum[i] = run; run += v; }
    }
}

__global__ __launch_bounds__(256) void scanC(
    const int* __restrict__ bsum, int* __restrict__ offsets,
    int* __restrict__ cursor, int n)
{
    const int i0 = blockIdx.x * SCB + threadIdx.x * 8;
    const int add = bsum[blockIdx.x];
    #pragma unroll
    for (int u = 0; u < 8; ++u) {
        int i = i0 + u;
        if (i < n) { int o = offsets[i] + add; offsets[i] = o; cursor[i] = o; }
    }
}

// ---------------------------------------------------------------------------
// Reorder edges into dst-node order.  pack = src(16b) | seg(8b)<<16.
// ---------------------------------------------------------------------------
__global__ __launch_bounds__(256) void reorder_kernel(
    const int* __restrict__ ei, const int* __restrict__ batch,
    int* __restrict__ cursor, unsigned* __restrict__ epack, int E, int N)
{
    int e = blockIdx.x * 256 + threadIdx.x;
    if (e >= E) return;
    int src = ei[e];
    int dst = ei[E + e];
    src = min(max(src, 0), N - 1);
    dst = min(max(dst, 0), N - 1);
    int seg = batch[src];
    seg = min(max(seg, 0), NSEG - 1);
    int pos = atomicAdd(&cursor[dst], 1);
    epack[pos] = (unsigned)src | ((unsigned)seg << 16);
}

// ---------------------------------------------------------------------------
// Score: persistent grid, one wave per dst node; q[dst] in registers across
// its edges; 4 edges in flight (16-lane groups, float4 k gathers, 4-step
// shuffle reduce).  Per-block LDS denom histogram flushed once.
// ---------------------------------------------------------------------------
__global__ __launch_bounds__(256) void score_kernel(
    const float* __restrict__ q, const float* __restrict__ k,
    const unsigned* __restrict__ epack,
    const int* __restrict__ offsets, const int* __restrict__ counts,
    float* __restrict__ exps, float* __restrict__ denom, int N)
{
    __shared__ float sden[NSEG];
    const int t = threadIdx.x;
    sden[t] = 0.f;
    __syncthreads();

    const int lane16 = t & 15;
    const int grp    = (t >> 4) & 3;
    const int wave   = t >> 6;
    const int nwaves = gridDim.x * 4;

    const float4* q4 = (const float4*)q;
    const float4* k4 = (const float4*)k;

    for (int n = blockIdx.x * 4 + wave; n < N; n += nwaves) {
        const int off = offsets[n];
        const int cnt = counts[n];
        if (cnt == 0) continue;
        const float4 qv = q4[(size_t)n * 16 + lane16];
        for (int i = grp; i < cnt; i += 4) {
            const int pos = off + i;
            const unsigned p = epack[pos];
            const int src = p & 0xFFFF;
            const float4 kv = k4[(size_t)src * 16 + lane16];
            float d = kv.x * qv.x + kv.y * qv.y + kv.z * qv.z + kv.w * qv.w;
            d += __shfl_xor(d, 1, 64);
            d += __shfl_xor(d, 2, 64);
            d += __shfl_xor(d, 4, 64);
            d += __shfl_xor(d, 8, 64);
            if (lane16 == 0) {
                float ex = __expf(d * 0.125f);
                exps[pos] = ex;
                atomicAdd(&sden[(p >> 16) & 255], ex);
            }
        }
    }
    __syncthreads();
    float ds = sden[t];
    if (ds != 0.f) atomicAdd(&denom[t], ds);
}

// ---------------------------------------------------------------------------
// Accumulate: one wave per dst node, lane = feature, register accumulator,
// zero atomics.  LDS reciprocal table; 8-wide unrolled edge loop.
// ---------------------------------------------------------------------------
__global__ __launch_bounds__(256) void accum_kernel(
    const float* __restrict__ v, const float* __restrict__ exps,
    const unsigned* __restrict__ epack,
    const int* __restrict__ offsets, const int* __restrict__ counts,
    const float* __restrict__ denom, float* __restrict__ out, int N)
{
    __shared__ float rden[NSEG];
    const int t = threadIdx.x;
    rden[t] = 1.0f / (denom[t] + 1e-6f);
    __syncthreads();

    const int lane = t & 63;
    const int wave = t >> 6;
    const int n = blockIdx.x * 4 + wave;
    if (n >= N) return;

    const int off = offsets[n];
    const int cnt = counts[n];

    float acc = 0.f;
    int i = 0;
    for (; i + 8 <= cnt; i += 8) {
        const uint4  pa = *(const uint4*)(epack + off + i);
        const uint4  pb = *(const uint4*)(epack + off + i + 4);
        const float4 ea = *(const float4*)(exps + off + i);
        const float4 eb = *(const float4*)(exps + off + i + 4);
        const float v0 = v[(size_t)(pa.x & 0xFFFF) * H + lane];
        const float v1 = v[(size_t)(pa.y & 0xFFFF) * H + lane];
        const float v2 = v[(size_t)(pa.z & 0xFFFF) * H + lane];
        const float v3 = v[(size_t)(pa.w & 0xFFFF) * H + lane];
        const float v4_ = v[(size_t)(pb.x & 0xFFFF) * H + lane];
        const float v5 = v[(size_t)(pb.y & 0xFFFF) * H + lane];
        const float v6 = v[(size_t)(pb.z & 0xFFFF) * H + lane];
        const float v7 = v[(size_t)(pb.w & 0xFFFF) * H + lane];
        acc = fmaf(v0, ea.x * rden[(pa.x >> 16) & 255], acc);
        acc = fmaf(v1, ea.y * rden[(pa.y >> 16) & 255], acc);
        acc = fmaf(v2, ea.z * rden[(pa.z >> 16) & 255], acc);
        acc = fmaf(v3, ea.w * rden[(pa.w >> 16) & 255], acc);
        acc = fmaf(v4_, eb.x * rden[(pb.x >> 16) & 255], acc);
        acc = fmaf(v5, eb.y * rden[(pb.y >> 16) & 255], acc);
        acc = fmaf(v6, eb.z * rden[(pb.z >> 16) & 255], acc);
        acc = fmaf(v7, eb.w * rden[(pb.w >> 16) & 255], acc);
    }
    for (; i + 4 <= cnt; i += 4) {
        const uint4  pp = *(const uint4*)(epack + off + i);
        const float4 ee = *(const float4*)(exps + off + i);
        const float v0 = v[(size_t)(pp.x & 0xFFFF) * H + lane];
        const float v1 = v[(size_t)(pp.y & 0xFFFF) * H + lane];
        const float v2 = v[(size_t)(pp.z & 0xFFFF) * H + lane];
        const float v3 = v[(size_t)(pp.w & 0xFFFF) * H + lane];
        acc = fmaf(v0, ee.x * rden[(pp.x >> 16) & 255], acc);
        acc = fmaf(v1, ee.y * rden[(pp.y >> 16) & 255], acc);
        acc = fmaf(v2, ee.z * rden[(pp.z >> 16) & 255], acc);
        acc = fmaf(v3, ee.w * rden[(pp.w >> 16) & 255], acc);
    }
    for (; i < cnt; ++i) {
        const unsigned p = epack[off + i];
        acc = fmaf(v[(size_t)(p & 0xFFFF) * H + lane],
                   exps[off + i] * rden[(p >> 16) & 255], acc);
    }
    out[(size_t)n * H + lane] = acc;
}

extern "C" void kernel_launch(void* const* d_in, const int* in_sizes, int n_in,
                              void* d_out, int out_size, void* d_ws, size_t ws_size,
                              hipStream_t stream)
{
    const float* x   = (const float*)d_in[0];
    const float* Wq  = (const float*)d_in[1];
    const float* bq  = (const float*)d_in[2];
    const float* Wk  = (const float*)d_in[3];
    const float* bk  = (const float*)d_in[4];
    const float* Wv  = (const float*)d_in[5];
    const float* bv  = (const float*)d_in[6];
    const int* ei    = (const int*)d_in[7];
    const int* batch = (const int*)d_in[8];

    const int N = in_sizes[8];        // 50000
    const int E = in_sizes[7] / 2;    // 800000
    const int EP = E + 3 * N + 16;    // padded edge-slot capacity

    float*    q       = (float*)d_ws;
    float*    k       = q + (size_t)N * H;
    float*    v       = k + (size_t)N * H;
    float*    exps    = v + (size_t)N * H;
    unsigned* epack   = (unsigned*)(exps + EP);
    int*      counts  = (int*)(epack + EP);
    int*      offsets = counts + N;
    int*      cursor  = offsets + N;
    int*      bsum    = cursor + N;
    float*    denom   = (float*)(bsum + 64);
    unsigned short* wt_hi = (unsigned short*)(denom + NSEG);
    unsigned short* wt_lo = wt_hi + 3 * H * F;

    hipMemsetAsync(counts, 0, N * sizeof(int), stream);
    hipMemsetAsync(denom, 0, NSEG * sizeof(float), stream);

    const int QB = (N + MB - 1) / MB;       // 782 (covers E/1024 hist chunks)
    const int NBSC = (N + SCB - 1) / SCB;   // 25 scan blocks

    w_convert<<<3 * H, 256, 0, stream>>>(Wq, Wk, Wv, wt_hi, wt_lo);

    qkv_mfma_hist<<<QB, 256, 0, stream>>>(
        x, wt_hi, wt_lo, bq, bk, bv, q, k, v, ei, counts, N, E);

    scanA<<<NBSC, 256, 0, stream>>>(counts, offsets, bsum, N);
    scanB<<<1, 64, 0, stream>>>(bsum, NBSC);
    scanC<<<NBSC, 256, 0, stream>>>(bsum, offsets, cursor, N);

    reorder_kernel<<<(E + 255) / 256, 256, 0, stream>>>(
        ei, batch, cursor, epack, E, N);

    score_kernel<<<2048, 256, 0, stream>>>(
        q, k, epack, offsets, counts, exps, denom, N);

    accum_kernel<<<(N + 3) / 4, 256, 0, stream>>>(
        v, exps, epack, offsets, counts, denom, (float*)d_out, N);
}

// Round 8
// 350.418 us; speedup vs baseline: 1.1830x; 1.1830x over previous
//
#include <hip/hip_runtime.h>

#define H    64
#define F    256
#define NSEG 256
#define SCB  2048   // scan elements per block
#define MB   64     // qkv node rows per block
#define KC   64     // qkv K chunk
#define XPAD 72     // LDS row stride in shorts (64 + 8: 16B-aligned, 2-way-free)

typedef float          f32x4v __attribute__((ext_vector_type(4)));
typedef short          bf16x8 __attribute__((ext_vector_type(8)));
typedef unsigned short u16x4  __attribute__((ext_vector_type(4)));

// ---------------------------------------------------------------------------
// Kernel 0: transpose+split W (3 x [256,64] fp32) into Wt[mat*64+j][k] bf16
// hi/lo (truncation split: w = hi + lo + O(2^-17)).  192 blocks = (mat,j).
// ---------------------------------------------------------------------------
__global__ __launch_bounds__(256) void w_convert(
    const float* __restrict__ Wq, const float* __restrict__ Wk,
    const float* __restrict__ Wv,
    unsigned short* __restrict__ wt_hi, unsigned short* __restrict__ wt_lo)
{
    const int b   = blockIdx.x;        // mat*64 + j
    const int mat = b >> 6;
    const int j   = b & 63;
    const int t   = threadIdx.x;       // k
    const float* W = (mat == 0) ? Wq : (mat == 1) ? Wk : Wv;
    float f = W[t * H + j];
    unsigned u = __float_as_uint(f);
    unsigned short hi = (unsigned short)(u >> 16);
    float rf = f - __uint_as_float(u & 0xFFFF0000u);
    unsigned short lo = (unsigned short)(__float_as_uint(rf) >> 16);
    const size_t o = (size_t)b * F + t;
    wt_hi[o] = hi;
    wt_lo[o] = lo;
}

// ---------------------------------------------------------------------------
// Kernel 1: QKV via split-bf16 MFMA, restructured (r7 was latency-dead:
// 16 barriers, dependent in-loop B loads, scalar u16 LDS writes).
// Wave w owns output-column tile nt=w (16 cols); computes all 4 m-tiles x
// 3 mats.  Per K-chunk (64): stage x hi/lo in LDS (short4 writes), preload
// ALL B frags for the chunk into registers (12x hi+lo independent 16B global
// loads, L1/L2-hot), then 72 MFMAs back-to-back.  8 barriers total.
//   acc += xh*wh + xh*wl + xl*wh    (xl*wl ~ 2^-17 dropped)
// Fused in-degree histogram rides along (fire-and-forget atomics).
// ---------------------------------------------------------------------------
__global__ __launch_bounds__(256) void qkv_mfma_hist(
    const float* __restrict__ x,
    const unsigned short* __restrict__ wt_hi,
    const unsigned short* __restrict__ wt_lo,
    const float* __restrict__ bq, const float* __restrict__ bk,
    const float* __restrict__ bv,
    float* __restrict__ q, float* __restrict__ k, float* __restrict__ v,
    const int* __restrict__ ei, int* __restrict__ counts,
    int N, int E)
{
    __shared__ unsigned short xs_hi[MB * XPAD];
    __shared__ unsigned short xs_lo[MB * XPAD];

    const int t = threadIdx.x;

    // --- fused histogram (independent; no result needed) ---
    {
        int e = blockIdx.x * 1024 + t;
        #pragma unroll
        for (int u = 0; u < 4; ++u) {
            if (e < E) {
                int dst = ei[E + e];
                dst = min(max(dst, 0), N - 1);
                atomicAdd(&counts[dst], 1);
            }
            e += 256;
        }
    }

    const int block0 = blockIdx.x * MB;
    const int rows = min(MB, N - block0);

    const int lane = t & 63;
    const int nt   = t >> 6;       // wave id = output col tile
    const int l15  = lane & 15;
    const int quad = lane >> 4;

    f32x4v acc[12];                // [mat*4 + mtile]
    #pragma unroll
    for (int i = 0; i < 12; ++i) acc[i] = (f32x4v)0.f;

    const size_t wbase = (size_t)(nt * 16 + l15) * F + quad * 8;

    for (int kb = 0; kb < F; kb += KC) {
        __syncthreads();                       // LDS reuse fence
        // --- stage x[block0..+64][kb..+64] as bf16 hi/lo, short4 writes ---
        #pragma unroll
        for (int it = 0; it < 4; ++it) {
            int idx = it * 256 + t;
            int r  = idx >> 4;                 // 16 float4 per row
            int c4 = idx & 15;
            float4 val = (r < rows)
                ? *(const float4*)(x + (size_t)(block0 + r) * F + kb + c4 * 4)
                : make_float4(0.f, 0.f, 0.f, 0.f);
            const float ff[4] = {val.x, val.y, val.z, val.w};
            u16x4 h, l;
            #pragma unroll
            for (int u = 0; u < 4; ++u) {
                unsigned ub = __float_as_uint(ff[u]);
                h[u] = (unsigned short)(ub >> 16);
                float rf = ff[u] - __uint_as_float(ub & 0xFFFF0000u);
                l[u] = (unsigned short)(__float_as_uint(rf) >> 16);
            }
            *(u16x4*)&xs_hi[r * XPAD + c4 * 4] = h;
            *(u16x4*)&xs_lo[r * XPAD + c4 * 4] = l;
        }
        __syncthreads();

        // --- preload ALL B frags for this chunk (independent loads) ---
        bf16x8 Bh[3][2], Bl[3][2];
        #pragma unroll
        for (int mat = 0; mat < 3; ++mat) {
            #pragma unroll
            for (int sk = 0; sk < 2; ++sk) {
                const size_t wo = wbase + (size_t)mat * 64 * F + kb + sk * 32;
                Bh[mat][sk] = *(const bf16x8*)(wt_hi + wo);
                Bl[mat][sk] = *(const bf16x8*)(wt_lo + wo);
            }
        }

        // --- MFMA burst: 2 subk x 4 mtiles x 3 mats x 3 split-terms ---
        #pragma unroll
        for (int sk = 0; sk < 2; ++sk) {
            #pragma unroll
            for (int mt = 0; mt < 4; ++mt) {
                const int ao = (mt * 16 + l15) * XPAD + sk * 32 + quad * 8;
                const bf16x8 ah = *(const bf16x8*)&xs_hi[ao];
                const bf16x8 al = *(const bf16x8*)&xs_lo[ao];
                #pragma unroll
                for (int mat = 0; mat < 3; ++mat) {
                    f32x4v a = acc[mat * 4 + mt];
                    a = __builtin_amdgcn_mfma_f32_16x16x32_bf16(ah, Bh[mat][sk], a, 0, 0, 0);
                    a = __builtin_amdgcn_mfma_f32_16x16x32_bf16(ah, Bl[mat][sk], a, 0, 0, 0);
                    a = __builtin_amdgcn_mfma_f32_16x16x32_bf16(al, Bh[mat][sk], a, 0, 0, 0);
                    acc[mat * 4 + mt] = a;
                }
            }
        }
    }

    // epilogue: C layout col = lane&15, row = quad*4 + reg  (m89-verified)
    float* outs[3] = {q, k, v};
    const float* biases[3] = {bq, bk, bv};
    const int col = nt * 16 + l15;
    #pragma unroll
    for (int mat = 0; mat < 3; ++mat) {
        float* dst = outs[mat];
        const float bb = biases[mat][col];
        #pragma unroll
        for (int mt = 0; mt < 4; ++mt) {
            #pragma unroll
            for (int r = 0; r < 4; ++r) {
                const int node = block0 + mt * 16 + quad * 4 + r;
                if (node < N)
                    dst[(size_t)node * H + col] = acc[mat * 4 + mt][r] + bb;
            }
        }
    }
}

// ---------------------------------------------------------------------------
// Scan phase A/B/C: exclusive scan of padded (x4) per-node counts.
// ---------------------------------------------------------------------------
__global__ __launch_bounds__(256) void scanA(
    const int* __restrict__ counts, int* __restrict__ offsets,
    int* __restrict__ bsum, int n)
{
    __shared__ int ps[256];
    const int t = threadIdx.x;
    const int i0 = blockIdx.x * SCB + t * 8;
    int loc[8];
    int s = 0;
    #pragma unroll
    for (int u = 0; u < 8; ++u) {
        int i = i0 + u;
        int c = (i < n) ? ((counts[i] + 3) & ~3) : 0;
        loc[u] = s; s += c;
    }
    ps[t] = s;
    __syncthreads();
    for (int off = 1; off < 256; off <<= 1) {
        int a = (t >= off) ? ps[t - off] : 0;
        __syncthreads();
        ps[t] += a;
        __syncthreads();
    }
    const int base = ps[t] - s;
    #pragma unroll
    for (int u = 0; u < 8; ++u) {
        int i = i0 + u;
        if (i < n) offsets[i] = base + loc[u];
    }
    if (t == 255) bsum[blockIdx.x] = ps[255];
}

__global__ void scanB(int* __restrict__ bsum, int nb)
{
    if (threadIdx.x == 0 && blockIdx.x == 0) {
        int run = 0;
        for (int i = 0; i < nb; ++i) { int v = bsum[i]; bsum[i] = run; run += v; }
    }
}

__global__ __launch_bounds__(256) void scanC(
    const int* __restrict__ bsum, int* __restrict__ offsets,
    int* __restrict__ cursor, int n)
{
    const int i0 = blockIdx.x * SCB + threadIdx.x * 8;
    const int add = bsum[blockIdx.x];
    #pragma unroll
    for (int u = 0; u < 8; ++u) {
        int i = i0 + u;
        if (i < n) { int o = offsets[i] + add; offsets[i] = o; cursor[i] = o; }
    }
}

// ---------------------------------------------------------------------------
// Reorder edges into dst-node order.  pack = src(16b) | seg(8b)<<16.
// ---------------------------------------------------------------------------
__global__ __launch_bounds__(256) void reorder_kernel(
    const int* __restrict__ ei, const int* __restrict__ batch,
    int* __restrict__ cursor, unsigned* __restrict__ epack, int E, int N)
{
    int e = blockIdx.x * 256 + threadIdx.x;
    if (e >= E) return;
    int src = ei[e];
    int dst = ei[E + e];
    src = min(max(src, 0), N - 1);
    dst = min(max(dst, 0), N - 1);
    int seg = batch[src];
    seg = min(max(seg, 0), NSEG - 1);
    int pos = atomicAdd(&cursor[dst], 1);
    epack[pos] = (unsigned)src | ((unsigned)seg << 16);
}

// ---------------------------------------------------------------------------
// Score: persistent grid, one wave per dst node; q[dst] in registers across
// its edges; 4 edges in flight (16-lane groups, float4 k gathers, 4-step
// shuffle reduce).  Per-block LDS denom histogram flushed once.
// ---------------------------------------------------------------------------
__global__ __launch_bounds__(256) void score_kernel(
    const float* __restrict__ q, const float* __restrict__ k,
    const unsigned* __restrict__ epack,
    const int* __restrict__ offsets, const int* __restrict__ counts,
    float* __restrict__ exps, float* __restrict__ denom, int N)
{
    __shared__ float sden[NSEG];
    const int t = threadIdx.x;
    sden[t] = 0.f;
    __syncthreads();

    const int lane16 = t & 15;
    const int grp    = (t >> 4) & 3;
    const int wave   = t >> 6;
    const int nwaves = gridDim.x * 4;

    const float4* q4 = (const float4*)q;
    const float4* k4 = (const float4*)k;

    for (int n = blockIdx.x * 4 + wave; n < N; n += nwaves) {
        const int off = offsets[n];
        const int cnt = counts[n];
        if (cnt == 0) continue;
        const float4 qv = q4[(size_t)n * 16 + lane16];
        for (int i = grp; i < cnt; i += 4) {
            const int pos = off + i;
            const unsigned p = epack[pos];
            const int src = p & 0xFFFF;
            const float4 kv = k4[(size_t)src * 16 + lane16];
            float d = kv.x * qv.x + kv.y * qv.y + kv.z * qv.z + kv.w * qv.w;
            d += __shfl_xor(d, 1, 64);
            d += __shfl_xor(d, 2, 64);
            d += __shfl_xor(d, 4, 64);
            d += __shfl_xor(d, 8, 64);
            if (lane16 == 0) {
                float ex = __expf(d * 0.125f);
                exps[pos] = ex;
                atomicAdd(&sden[(p >> 16) & 255], ex);
            }
        }
    }
    __syncthreads();
    float ds = sden[t];
    if (ds != 0.f) atomicAdd(&denom[t], ds);
}

// ---------------------------------------------------------------------------
// Accumulate: one wave per dst node, lane = feature, register accumulator,
// zero atomics.  LDS reciprocal table; 8-wide unrolled edge loop.
// ---------------------------------------------------------------------------
__global__ __launch_bounds__(256) void accum_kernel(
    const float* __restrict__ v, const float* __restrict__ exps,
    const unsigned* __restrict__ epack,
    const int* __restrict__ offsets, const int* __restrict__ counts,
    const float* __restrict__ denom, float* __restrict__ out, int N)
{
    __shared__ float rden[NSEG];
    const int t = threadIdx.x;
    rden[t] = 1.0f / (denom[t] + 1e-6f);
    __syncthreads();

    const int lane = t & 63;
    const int wave = t >> 6;
    const int n = blockIdx.x * 4 + wave;
    if (n >= N) return;

    const int off = offsets[n];
    const int cnt = counts[n];

    float acc = 0.f;
    int i = 0;
    for (; i + 8 <= cnt; i += 8) {
        const uint4  pa = *(const uint4*)(epack + off + i);
        const uint4  pb = *(const uint4*)(epack + off + i + 4);
        const float4 ea = *(const float4*)(exps + off + i);
        const float4 eb = *(const float4*)(exps + off + i + 4);
        const float v0 = v[(size_t)(pa.x & 0xFFFF) * H + lane];
        const float v1 = v[(size_t)(pa.y & 0xFFFF) * H + lane];
        const float v2 = v[(size_t)(pa.z & 0xFFFF) * H + lane];
        const float v3 = v[(size_t)(pa.w & 0xFFFF) * H + lane];
        const float v4_ = v[(size_t)(pb.x & 0xFFFF) * H + lane];
        const float v5 = v[(size_t)(pb.y & 0xFFFF) * H + lane];
        const float v6 = v[(size_t)(pb.z & 0xFFFF) * H + lane];
        const float v7 = v[(size_t)(pb.w & 0xFFFF) * H + lane];
        acc = fmaf(v0, ea.x * rden[(pa.x >> 16) & 255], acc);
        acc = fmaf(v1, ea.y * rden[(pa.y >> 16) & 255], acc);
        acc = fmaf(v2, ea.z * rden[(pa.z >> 16) & 255], acc);
        acc = fmaf(v3, ea.w * rden[(pa.w >> 16) & 255], acc);
        acc = fmaf(v4_, eb.x * rden[(pb.x >> 16) & 255], acc);
        acc = fmaf(v5, eb.y * rden[(pb.y >> 16) & 255], acc);
        acc = fmaf(v6, eb.z * rden[(pb.z >> 16) & 255], acc);
        acc = fmaf(v7, eb.w * rden[(pb.w >> 16) & 255], acc);
    }
    for (; i + 4 <= cnt; i += 4) {
        const uint4  pp = *(const uint4*)(epack + off + i);
        const float4 ee = *(const float4*)(exps + off + i);
        const float v0 = v[(size_t)(pp.x & 0xFFFF) * H + lane];
        const float v1 = v[(size_t)(pp.y & 0xFFFF) * H + lane];
        const float v2 = v[(size_t)(pp.z & 0xFFFF) * H + lane];
        const float v3 = v[(size_t)(pp.w & 0xFFFF) * H + lane];
        acc = fmaf(v0, ee.x * rden[(pp.x >> 16) & 255], acc);
        acc = fmaf(v1, ee.y * rden[(pp.y >> 16) & 255], acc);
        acc = fmaf(v2, ee.z * rden[(pp.z >> 16) & 255], acc);
        acc = fmaf(v3, ee.w * rden[(pp.w >> 16) & 255], acc);
    }
    for (; i < cnt; ++i) {
        const unsigned p = epack[off + i];
        acc = fmaf(v[(size_t)(p & 0xFFFF) * H + lane],
                   exps[off + i] * rden[(p >> 16) & 255], acc);
    }
    out[(size_t)n * H + lane] = acc;
}

extern "C" void kernel_launch(void* const* d_in, const int* in_sizes, int n_in,
                              void* d_out, int out_size, void* d_ws, size_t ws_size,
                              hipStream_t stream)
{
    const float* x   = (const float*)d_in[0];
    const float* Wq  = (const float*)d_in[1];
    const float* bq  = (const float*)d_in[2];
    const float* Wk  = (const float*)d_in[3];
    const float* bk  = (const float*)d_in[4];
    const float* Wv  = (const float*)d_in[5];
    const float* bv  = (const float*)d_in[6];
    const int* ei    = (const int*)d_in[7];
    const int* batch = (const int*)d_in[8];

    const int N = in_sizes[8];        // 50000
    const int E = in_sizes[7] / 2;    // 800000
    const int EP = E + 3 * N + 16;    // padded edge-slot capacity

    float*    q       = (float*)d_ws;
    float*    k       = q + (size_t)N * H;
    float*    v       = k + (size_t)N * H;
    float*    exps    = v + (size_t)N * H;
    unsigned* epack   = (unsigned*)(exps + EP);
    int*      counts  = (int*)(epack + EP);
    int*      offsets = counts + N;
    int*      cursor  = offsets + N;
    int*      bsum    = cursor + N;
    float*    denom   = (float*)(bsum + 64);
    unsigned short* wt_hi = (unsigned short*)(denom + NSEG);
    unsigned short* wt_lo = wt_hi + 3 * H * F;

    hipMemsetAsync(counts, 0, N * sizeof(int), stream);
    hipMemsetAsync(denom, 0, NSEG * sizeof(float), stream);

    const int QB = (N + MB - 1) / MB;       // 782 (covers E/1024 hist chunks)
    const int NBSC = (N + SCB - 1) / SCB;   // 25 scan blocks

    w_convert<<<3 * H, 256, 0, stream>>>(Wq, Wk, Wv, wt_hi, wt_lo);

    qkv_mfma_hist<<<QB, 256, 0, stream>>>(
        x, wt_hi, wt_lo, bq, bk, bv, q, k, v, ei, counts, N, E);

    scanA<<<NBSC, 256, 0, stream>>>(counts, offsets, bsum, N);
    scanB<<<1, 64, 0, stream>>>(bsum, NBSC);
    scanC<<<NBSC, 256, 0, stream>>>(bsum, offsets, cursor, N);

    reorder_kernel<<<(E + 255) / 256, 256, 0, stream>>>(
        ei, batch, cursor, epack, E, N);

    score_kernel<<<2048, 256, 0, stream>>>(
        q, k, epack, offsets, counts, exps, denom, N);

    accum_kernel<<<(N + 3) / 4, 256, 0, stream>>>(
        v, exps, epack, offsets, counts, denom, (float*)d_out, N);
}